// Round 6
// baseline (2988.486 us; speedup 1.0000x reference)
//
#include <hip/hip_runtime.h>

typedef __attribute__((ext_vector_type(8))) short short8;
typedef __attribute__((ext_vector_type(4))) float floatx4;

#define NSTEPS 5
#define DD 512
#define ANN 256
#define NNODE 2048
#define NEDGE 8                 // 2*E
#define NCOLS (NNODE * NEDGE)   // 16384
#define MAXE 96                 // nnz per (node,edge-type): mean 30.7, sd 5.5
#define KP (NEDGE * DD)         // 4096

// Fragment-ordered (FO) layout for [M][K] bf16 operands:
// flat = ((rowtile * (K/8) + kchunk) * 16 + row%16) * 8 + k%8
// => one 16x16x32 MFMA fragment (rowtile, kchunk0..+3) is a contiguous 1KB
//    block where lane l's 16B sits at base + l*16.

typedef __attribute__((address_space(3))) unsigned lds_u32;
typedef const __attribute__((address_space(1))) unsigned g_u32;

__device__ __forceinline__ void gload16(const short* g, short* l) {
    __builtin_amdgcn_global_load_lds((g_u32*)g, (lds_u32*)l, 16, 0, 0);
}

__device__ inline float bf2f(unsigned short s) {
    unsigned u = ((unsigned)s) << 16;
    float f; __builtin_memcpy(&f, &u, 4);
    return f;
}
__device__ inline unsigned short f2bf(float f) {   // round-to-nearest-even
    unsigned u; __builtin_memcpy(&u, &f, 4);
    u += 0x7fffu + ((u >> 16) & 1u);
    return (unsigned short)(u >> 16);
}
__device__ inline void split2(float x, unsigned short& hi, unsigned short& lo) {
    hi = f2bf(x);
    lo = f2bf(x - bf2f(hi));
}
// split-write one element into an FO pair with K=512
__device__ inline void fo_write(short* __restrict__ Fhi, short* __restrict__ Flo,
                                int row, int col, float v) {
    unsigned short hs, ls;
    split2(v, hs, ls);
    size_t a = ((size_t)(row >> 4) * 64 + (col >> 3)) * 128 + ((row & 15) << 3) + (col & 7);
    Fhi[a] = (short)hs;
    Flo[a] = (short)ls;
}

// h = [ann | 0] fp32; HB (FO, K=512) = split(h); cnt2 = 0
__global__ __launch_bounds__(256) void k_init(const float* __restrict__ ann,
                                              float* __restrict__ h,
                                              short* __restrict__ HBhi,
                                              short* __restrict__ HBlo,
                                              int* __restrict__ cnt2) {
    int n = blockIdx.x, t = threadIdx.x;
    int c = 2 * t;
    float v0 = 0.f, v1 = 0.f;
    if (c < ANN) {
        v0 = ann[(size_t)n * ANN + c];
        v1 = ann[(size_t)n * ANN + c + 1];
    }
    h[(size_t)n * DD + c]     = v0;
    h[(size_t)n * DD + c + 1] = v1;
    unsigned short h0, l0, h1, l1;
    split2(v0, h0, l0);
    split2(v1, h1, l1);
    size_t a = ((size_t)(n >> 4) * 64 + (t >> 2)) * 128 + ((n & 15) << 3) + ((t & 3) << 1);
    *(unsigned*)(HBhi + a) = (unsigned)h0 | ((unsigned)h1 << 16);
    *(unsigned*)(HBlo + a) = (unsigned)l0 | ((unsigned)l1 << 16);
    if (t < NEDGE) cnt2[n * NEDGE + t] = 0;
}

// fp32 0/1 adjacency -> per-(row, edge-type) source-node index lists
__global__ __launch_bounds__(256) void k_build(const float* __restrict__ adj,
                                               int* __restrict__ cnt2,
                                               unsigned short* __restrict__ idx) {
    int n = blockIdx.x;
    const float* row = adj + (size_t)n * NCOLS;
    for (int j8 = threadIdx.x; j8 < NCOLS / 8; j8 += 256) {
        floatx4 a = *(const floatx4*)(row + j8 * 8);
        floatx4 b = *(const floatx4*)(row + j8 * 8 + 4);
        unsigned nz = 0;
        #pragma unroll
        for (int i = 0; i < 4; i++) {
            if (a[i] != 0.f) nz |= 1u << i;
            if (b[i] != 0.f) nz |= 1u << (4 + i);
        }
        while (nz) {
            int i = __builtin_ctz(nz);
            nz &= nz - 1;
            int j = j8 * 8 + i;
            int e = j >> 11;
            int m = j & (NNODE - 1);
            int p = atomicAdd(&cnt2[n * NEDGE + e], 1);
            if (p < MAXE) idx[((size_t)n * NEDGE + e) * MAXE + p] = (unsigned short)m;
        }
    }
}

// Transpose+split weights into FO [N/16][K/8][16][8], contiguous-K source [K][512]
__global__ __launch_bounds__(256) void k_transP(const float* __restrict__ W,
                                                short* __restrict__ Fhi,
                                                short* __restrict__ Flo, int K) {
    __shared__ float st[32][33];
    int tx = threadIdx.x & 31, ty = threadIdx.x >> 5;
    int k0 = blockIdx.x * 32, n0 = blockIdx.y * 32;
    #pragma unroll
    for (int i = 0; i < 4; i++)
        st[ty + i * 8][tx] = W[(size_t)(k0 + ty + i * 8) * DD + n0 + tx];
    __syncthreads();
    #pragma unroll
    for (int i = 0; i < 4; i++) {
        int n = n0 + ty + i * 8, k = k0 + tx;
        float v = st[tx][ty + i * 8];
        unsigned short hs, ls;
        split2(v, hs, ls);
        size_t a = ((size_t)(n >> 4) * (K >> 3) + (k >> 3)) * 128 + ((n & 15) << 3) + (k & 7);
        Fhi[a] = (short)hs;
        Flo[a] = (short)ls;
    }
}

// Same, 4-quadrant source (k-half x n-half), K=1024
__global__ __launch_bounds__(256) void k_transG(const float* __restrict__ s00,
                                                const float* __restrict__ s10,
                                                const float* __restrict__ s01,
                                                const float* __restrict__ s11,
                                                short* __restrict__ Fhi,
                                                short* __restrict__ Flo) {
    __shared__ float st[32][33];
    const int K = 2 * DD;
    int tx = threadIdx.x & 31, ty = threadIdx.x >> 5;
    int k0 = blockIdx.x * 32, n0 = blockIdx.y * 32;
    const float* sk0 = (n0 < DD) ? s00 : s01;
    const float* sk1 = (n0 < DD) ? s10 : s11;
    #pragma unroll
    for (int i = 0; i < 4; i++) {
        int k = k0 + ty + i * 8;
        const float* s = (k < DD) ? sk0 : sk1;
        st[ty + i * 8][tx] = s[(size_t)(k & (DD - 1)) * DD + ((n0 + tx) & (DD - 1))];
    }
    __syncthreads();
    #pragma unroll
    for (int i = 0; i < 4; i++) {
        int n = n0 + ty + i * 8, k = k0 + tx;
        float v = st[tx][ty + i * 8];
        unsigned short hs, ls;
        split2(v, hs, ls);
        size_t a = ((size_t)(n >> 4) * (K >> 3) + (k >> 3)) * 128 + ((n & 15) << 3) + (k & 7);
        Fhi[a] = (short)hs;
        Flo[a] = (short)ls;
    }
}

// All-edge gather: Gbig (FO, K=4096) = split(per-edge neighbor sums of h);
// abuf = deg-weighted prop bias.
__global__ __launch_bounds__(256) void k_gather_all(const float* __restrict__ h,
                                                    const int* __restrict__ cnt2,
                                                    const unsigned short* __restrict__ idx,
                                                    const float* __restrict__ bp,
                                                    short* __restrict__ Gbhi,
                                                    short* __restrict__ Gblo,
                                                    float* __restrict__ abuf) {
    int n = blockIdx.x, t = threadIdx.x;
    float s0 = 0.f, s1 = 0.f;
    size_t abase = ((size_t)(n >> 4) * 512) * 128 + ((n & 15) << 3) + ((t & 3) << 1);
    #pragma unroll 1
    for (int e = 0; e < NEDGE; e++) {
        int m = cnt2[n * NEDGE + e];
        float deg = (float)m;
        if (m > MAXE) m = MAXE;
        const unsigned short* row = idx + ((size_t)n * NEDGE + e) * MAXE;
        float a0 = 0.f, a1 = 0.f;
        int i = 0;
        for (; i + 4 <= m; i += 4) {
            const float* h0 = h + (size_t)row[i]     * DD + 2 * t;
            const float* h1 = h + (size_t)row[i + 1] * DD + 2 * t;
            const float* h2 = h + (size_t)row[i + 2] * DD + 2 * t;
            const float* h3 = h + (size_t)row[i + 3] * DD + 2 * t;
            a0 += h0[0] + h1[0] + h2[0] + h3[0];
            a1 += h0[1] + h1[1] + h2[1] + h3[1];
        }
        for (; i < m; i++) {
            const float* hp = h + (size_t)row[i] * DD + 2 * t;
            a0 += hp[0];
            a1 += hp[1];
        }
        unsigned short h0s, l0s, h1s, l1s;
        split2(a0, h0s, l0s);
        split2(a1, h1s, l1s);
        size_t a = abase + (size_t)(e * 64 + (t >> 2)) * 128;
        *(unsigned*)(Gbhi + a) = (unsigned)h0s | ((unsigned)h1s << 16);
        *(unsigned*)(Gblo + a) = (unsigned)l0s | ((unsigned)l1s << 16);
        s0 += deg * bp[e * DD + 2 * t];
        s1 += deg * bp[e * DD + 2 * t + 1];
    }
    abuf[(size_t)n * DD + 2 * t]     = s0;
    abuf[(size_t)n * DD + 2 * t + 1] = s1;
}

// Split-bf16 MFMA GEMM on FO operands. Block 64x64, 4 waves (2x2), wave tile 32x32.
// Double-buffered LDS, one barrier/iter, staging via global_load_lds(16B).
// C = (Ahi+Alo)@(Bhi+Blo)^T (3 products, fp32 acc).
// MODE 0 (prop): K=4096, A=Gbig. v += abuf; Ga FO = split(v).
// MODE 1 (zr):   K=1024 (A seg: Ga | HB), N=1024. col<512: zbuf = sigmoid(v+bz);
//                col>=512: RH FO = split(sigmoid(v+br)*h).
// MODE 2 (fin):  K=1024 (A seg: Ga | RH). hn=(1-z)h+z*tanh(v+bh); h, HB FO, outF.
template<int MODE>
__global__ __launch_bounds__(256, 2) void k_gemm4(
    const short* __restrict__ A0hi, const short* __restrict__ A0lo,
    const short* __restrict__ A1hi, const short* __restrict__ A1lo,
    const short* __restrict__ Bhi,  const short* __restrict__ Blo, int K,
    const float* __restrict__ bias0, const float* __restrict__ bias1,
    float* __restrict__ zbuf,
    float* __restrict__ h,
    short* __restrict__ Ohi, short* __restrict__ Olo,
    float* __restrict__ outF) {

    __shared__ short S[2][16][512];   // 2 bufs x 16 slots x 1KB

    const int tid = threadIdx.x;
    const int lane = tid & 63;
    const int wave = tid >> 6;
    const int wm = wave >> 1;
    const int wn = wave & 1;
    const int quad = lane >> 4;
    const int l16 = lane & 15;
    const int blockM = blockIdx.y * 64;
    const int blockN = blockIdx.x * 64;
    const int mt0 = blockM >> 4, nt0 = blockN >> 4;
    const int Kc = K >> 3;

    floatx4 acc[2][2];
    #pragma unroll
    for (int mi = 0; mi < 2; mi++)
        #pragma unroll
        for (int ni = 0; ni < 2; ni++)
            acc[mi][ni] = (floatx4){0.f, 0.f, 0.f, 0.f};

    // stage 4 slots for this wave into S[buf]: slots wave*4 .. wave*4+3
    auto stage = [&](int k0, int buf) {
        #pragma unroll
        for (int j = 0; j < 4; j++) {
            int s = wave * 4 + j;
            const short* g;
            if (s < 8) {                     // A slots: pl*4 + mt
                int pl = s >> 2, mt = s & 3;
                const short* base;
                int kc, segk3;
                if (MODE == 0) {
                    base = pl ? A0lo : A0hi;
                    kc = k0 >> 3;
                    segk3 = Kc;
                } else {
                    int seg = k0 >> 9;
                    base = seg ? (pl ? A1lo : A1hi) : (pl ? A0lo : A0hi);
                    kc = (k0 & 511) >> 3;
                    segk3 = 64;
                }
                g = base + ((size_t)(mt0 + mt) * segk3 + kc) * 128;
            } else {                         // B slots: 8 + pl*4 + nt
                int u = s - 8, pl = u >> 2, nt = u & 3;
                const short* base = pl ? Blo : Bhi;
                g = base + ((size_t)(nt0 + nt) * Kc + (k0 >> 3)) * 128;
            }
            gload16(g + lane * 8, &S[buf][s][lane * 8]);
        }
    };

    stage(0, 0);
    for (int k0 = 0; k0 < K; k0 += 32) {
        int buf = (k0 >> 5) & 1;
        __syncthreads();                    // drains this buf's DMA; prev reads done
        if (k0 + 32 < K) stage(k0 + 32, buf ^ 1);

        short8 ah[2], al[2], bh[2], bl[2];
        #pragma unroll
        for (int mi = 0; mi < 2; mi++) {
            ah[mi] = *(const short8*)&S[buf][0 + wm * 2 + mi][lane * 8];
            al[mi] = *(const short8*)&S[buf][4 + wm * 2 + mi][lane * 8];
        }
        #pragma unroll
        for (int ni = 0; ni < 2; ni++) {
            bh[ni] = *(const short8*)&S[buf][8  + wn * 2 + ni][lane * 8];
            bl[ni] = *(const short8*)&S[buf][12 + wn * 2 + ni][lane * 8];
        }
        #pragma unroll
        for (int mi = 0; mi < 2; mi++)
            #pragma unroll
            for (int ni = 0; ni < 2; ni++) {
                acc[mi][ni] = __builtin_amdgcn_mfma_f32_16x16x32_bf16(ah[mi], bh[ni], acc[mi][ni], 0, 0, 0);
                acc[mi][ni] = __builtin_amdgcn_mfma_f32_16x16x32_bf16(ah[mi], bl[ni], acc[mi][ni], 0, 0, 0);
                acc[mi][ni] = __builtin_amdgcn_mfma_f32_16x16x32_bf16(al[mi], bh[ni], acc[mi][ni], 0, 0, 0);
            }
    }

    // C/D layout (m89-verified): elem r -> row = quad*4+r, col = l16
    #pragma unroll
    for (int mi = 0; mi < 2; mi++) {
        #pragma unroll
        for (int ni = 0; ni < 2; ni++) {
            int gcol = blockN + wn * 32 + ni * 16 + l16;
            #pragma unroll
            for (int r = 0; r < 4; r++) {
                int grow = blockM + wm * 32 + mi * 16 + quad * 4 + r;
                float v = acc[mi][ni][r];
                if (MODE == 0) {
                    size_t o = (size_t)grow * DD + gcol;
                    fo_write(Ohi, Olo, grow, gcol, v + zbuf[o]);
                } else if (MODE == 1) {
                    if (gcol < DD) {
                        size_t o = (size_t)grow * DD + gcol;
                        zbuf[o] = 1.f / (1.f + __expf(-(v + bias0[gcol])));
                    } else {
                        int c = gcol - DD;
                        size_t o = (size_t)grow * DD + c;
                        float rr = 1.f / (1.f + __expf(-(v + bias1[c])));
                        fo_write(Ohi, Olo, grow, c, rr * h[o]);
                    }
                } else {
                    size_t o = (size_t)grow * DD + gcol;
                    float zv = zbuf[o];
                    float hv = h[o];
                    float hn = (1.f - zv) * hv + zv * tanhf(v + bias0[gcol]);
                    h[o] = hn;
                    fo_write(Ohi, Olo, grow, gcol, hn);
                    outF[o] = hn;
                }
            }
        }
    }
}

extern "C" void kernel_launch(void* const* d_in, const int* in_sizes, int n_in,
                              void* d_out, int out_size, void* d_ws, size_t ws_size,
                              hipStream_t stream) {
    const float* adj = (const float*)d_in[0];
    const float* ann = (const float*)d_in[1];
    const float* Wp  = (const float*)d_in[2];
    const float* bp  = (const float*)d_in[3];
    const float* Wz  = (const float*)d_in[4];
    const float* Uz  = (const float*)d_in[5];
    const float* bz  = (const float*)d_in[6];
    const float* Wr  = (const float*)d_in[7];
    const float* Ur  = (const float*)d_in[8];
    const float* br  = (const float*)d_in[9];
    const float* Wh  = (const float*)d_in[10];
    const float* Uh  = (const float*)d_in[11];
    const float* bh  = (const float*)d_in[12];

    // workspace carve (~81 MB; ws ~512 MB per round-4 fill counters)
    char* p = (char*)d_ws;
    float* h     = (float*)p; p += (size_t)NNODE * DD * 4;          // 4 MB
    float* abuf  = (float*)p; p += (size_t)NNODE * DD * 4;          // 4 MB deg-bias -> z
    short* Gbhi  = (short*)p; p += (size_t)NNODE * KP * 2;          // 16 MB (FO K=4096)
    short* Gblo  = (short*)p; p += (size_t)NNODE * KP * 2;          // 16 MB
    short* Gahi  = (short*)p; p += (size_t)NNODE * DD * 2;          // 2 MB (FO K=512)
    short* Galo  = (short*)p; p += (size_t)NNODE * DD * 2;
    short* HBhi  = (short*)p; p += (size_t)NNODE * DD * 2;
    short* HBlo  = (short*)p; p += (size_t)NNODE * DD * 2;
    short* RHhi  = (short*)p; p += (size_t)NNODE * DD * 2;
    short* RHlo  = (short*)p; p += (size_t)NNODE * DD * 2;
    short* WpThi = (short*)p; p += (size_t)DD * KP * 2;             // 4 MB (FO N=512,K=4096)
    short* WpTlo = (short*)p; p += (size_t)DD * KP * 2;
    short* ZRhi  = (short*)p; p += (size_t)(2 * DD) * (2 * DD) * 2; // 2 MB (FO N=1024,K=1024)
    short* ZRlo  = (short*)p; p += (size_t)(2 * DD) * (2 * DD) * 2;
    short* HThi  = (short*)p; p += (size_t)DD * (2 * DD) * 2;       // 1 MB (FO N=512,K=1024)
    short* HTlo  = (short*)p; p += (size_t)DD * (2 * DD) * 2;
    unsigned short* idx = (unsigned short*)p;
    p += (size_t)NNODE * NEDGE * MAXE * 2;                          // 3 MB
    int* cnt2 = (int*)p; p += (size_t)NNODE * NEDGE * 4;

    float* outF = (float*)d_out;

    k_init<<<NNODE, 256, 0, stream>>>(ann, h, HBhi, HBlo, cnt2);
    k_build<<<NNODE, 256, 0, stream>>>(adj, cnt2, idx);
    k_transP<<<dim3(KP / 32, DD / 32), 256, 0, stream>>>(Wp, WpThi, WpTlo, KP);
    k_transG<<<dim3(32, 32), 256, 0, stream>>>(Wz, Uz, Wr, Ur, ZRhi, ZRlo);
    k_transG<<<dim3(32, 16), 256, 0, stream>>>(Wh, Uh, Wh, Uh, HThi, HTlo);

    dim3 gP(DD / 64, NNODE / 64);        // (8, 32)  = 256 blocks
    dim3 gZ(2 * DD / 64, NNODE / 64);    // (16, 32) = 512 blocks
    for (int s = 0; s < NSTEPS; s++) {
        k_gather_all<<<NNODE, 256, 0, stream>>>(h, cnt2, idx, bp, Gbhi, Gblo, abuf);
        // a = Gbig @ WpT + deg-bias -> Ga FO
        k_gemm4<0><<<gP, 256, 0, stream>>>(Gbhi, Gblo, nullptr, nullptr,
                                           WpThi, WpTlo, KP, nullptr, nullptr,
                                           abuf, nullptr, Gahi, Galo, nullptr);
        // [z|r]: z -> abuf, RH FO = split(r*h)
        k_gemm4<1><<<gZ, 256, 0, stream>>>(Gahi, Galo, HBhi, HBlo,
                                           ZRhi, ZRlo, 2 * DD, bz, br,
                                           abuf, h, RHhi, RHlo, nullptr);
        // h' = (1-z)h + z*tanh([a|rh]@[Wh;Uh]+bh) -> h, HB FO, d_out
        k_gemm4<2><<<gP, 256, 0, stream>>>(Gahi, Galo, RHhi, RHlo,
                                           HThi, HTlo, 2 * DD, bh, nullptr,
                                           abuf, h, HBhi, HBlo, outF);
    }
}

// Round 8
// 1547.479 us; speedup vs baseline: 1.9312x; 1.9312x over previous
//
#include <hip/hip_runtime.h>

typedef __attribute__((ext_vector_type(8))) short short8;
typedef __attribute__((ext_vector_type(4))) float floatx4;

#define NSTEPS 5
#define DD 512
#define ANN 256
#define NNODE 2048
#define NEDGE 8                 // 2*E
#define NCOLS (NNODE * NEDGE)   // 16384
#define MAXE 96                 // nnz per (node,edge-type): mean 30.7, sd 5.5
#define KP (NEDGE * DD)         // 4096

// Fragment-ordered (FO) layout for [M][K] bf16:
// addr(row,k) = ((row>>4)*(K>>3) + (k>>3))*128 + ((row&15)<<3) + (k&7)
// One slot = 16 rows x 32 k = 1KB, lane l's 16B at slot_base + l*16.

__device__ inline float bf2f(unsigned short s) {
    unsigned u = ((unsigned)s) << 16;
    float f; __builtin_memcpy(&f, &u, 4);
    return f;
}
__device__ inline unsigned short f2bf(float f) {   // round-to-nearest-even
    unsigned u; __builtin_memcpy(&u, &f, 4);
    u += 0x7fffu + ((u >> 16) & 1u);
    return (unsigned short)(u >> 16);
}
__device__ inline void split2(float x, unsigned short& hi, unsigned short& lo) {
    hi = f2bf(x);
    lo = f2bf(x - bf2f(hi));
}
// split-write one element into FO hi/lo planes (K=512)
__device__ inline void fo_write(short* __restrict__ Fhi, short* __restrict__ Flo,
                                int row, int col, float v) {
    unsigned short hs, ls;
    split2(v, hs, ls);
    size_t a = ((size_t)(row >> 4) * 64 + (col >> 3)) * 128 + ((row & 15) << 3) + (col & 7);
    Fhi[a] = (short)hs;
    Flo[a] = (short)ls;
}

// h = [ann | 0] fp32; HB (FO, K=512) = split(h); cnt2 = 0
__global__ __launch_bounds__(256) void k_init(const float* __restrict__ ann,
                                              float* __restrict__ h,
                                              short* __restrict__ HBhi,
                                              short* __restrict__ HBlo,
                                              int* __restrict__ cnt2) {
    int n = blockIdx.x, t = threadIdx.x;
    int c = 2 * t;
    float v0 = 0.f, v1 = 0.f;
    if (c < ANN) {
        v0 = ann[(size_t)n * ANN + c];
        v1 = ann[(size_t)n * ANN + c + 1];
    }
    h[(size_t)n * DD + c]     = v0;
    h[(size_t)n * DD + c + 1] = v1;
    unsigned short h0, l0, h1, l1;
    split2(v0, h0, l0);
    split2(v1, h1, l1);
    size_t a = ((size_t)(n >> 4) * 64 + (t >> 2)) * 128 + ((n & 15) << 3) + ((t & 3) << 1);
    *(unsigned*)(HBhi + a) = (unsigned)h0 | ((unsigned)h1 << 16);
    *(unsigned*)(HBlo + a) = (unsigned)l0 | ((unsigned)l1 << 16);
    if (t < NEDGE) cnt2[n * NEDGE + t] = 0;
}

// fp32 0/1 adjacency -> per-(row, edge-type) source-node index lists
__global__ __launch_bounds__(256) void k_build(const float* __restrict__ adj,
                                               int* __restrict__ cnt2,
                                               unsigned short* __restrict__ idx) {
    int n = blockIdx.x;
    const float* row = adj + (size_t)n * NCOLS;
    for (int j8 = threadIdx.x; j8 < NCOLS / 8; j8 += 256) {
        floatx4 a = *(const floatx4*)(row + j8 * 8);
        floatx4 b = *(const floatx4*)(row + j8 * 8 + 4);
        unsigned nz = 0;
        #pragma unroll
        for (int i = 0; i < 4; i++) {
            if (a[i] != 0.f) nz |= 1u << i;
            if (b[i] != 0.f) nz |= 1u << (4 + i);
        }
        while (nz) {
            int i = __builtin_ctz(nz);
            nz &= nz - 1;
            int j = j8 * 8 + i;
            int e = j >> 11;
            int m = j & (NNODE - 1);
            int p = atomicAdd(&cnt2[n * NEDGE + e], 1);
            if (p < MAXE) idx[((size_t)n * NEDGE + e) * MAXE + p] = (unsigned short)m;
        }
    }
}

// Transpose+split weights into FO (hi & lo), contiguous-K source [K][512]
__global__ __launch_bounds__(256) void k_transP(const float* __restrict__ W,
                                                short* __restrict__ Fhi,
                                                short* __restrict__ Flo, int K) {
    __shared__ float st[32][33];
    int tx = threadIdx.x & 31, ty = threadIdx.x >> 5;
    int k0 = blockIdx.x * 32, n0 = blockIdx.y * 32;
    #pragma unroll
    for (int i = 0; i < 4; i++)
        st[ty + i * 8][tx] = W[(size_t)(k0 + ty + i * 8) * DD + n0 + tx];
    __syncthreads();
    #pragma unroll
    for (int i = 0; i < 4; i++) {
        int n = n0 + ty + i * 8, k = k0 + tx;
        float v = st[tx][ty + i * 8];
        unsigned short hs, ls;
        split2(v, hs, ls);
        size_t a = ((size_t)(n >> 4) * (K >> 3) + (k >> 3)) * 128 + ((n & 15) << 3) + (k & 7);
        Fhi[a] = (short)hs;
        Flo[a] = (short)ls;
    }
}

// Same, 4-quadrant source (k-half x n-half), K=1024
__global__ __launch_bounds__(256) void k_transG(const float* __restrict__ s00,
                                                const float* __restrict__ s10,
                                                const float* __restrict__ s01,
                                                const float* __restrict__ s11,
                                                short* __restrict__ Fhi,
                                                short* __restrict__ Flo) {
    __shared__ float st[32][33];
    const int K = 2 * DD;
    int tx = threadIdx.x & 31, ty = threadIdx.x >> 5;
    int k0 = blockIdx.x * 32, n0 = blockIdx.y * 32;
    const float* sk0 = (n0 < DD) ? s00 : s01;
    const float* sk1 = (n0 < DD) ? s10 : s11;
    #pragma unroll
    for (int i = 0; i < 4; i++) {
        int k = k0 + ty + i * 8;
        const float* s = (k < DD) ? sk0 : sk1;
        st[ty + i * 8][tx] = s[(size_t)(k & (DD - 1)) * DD + ((n0 + tx) & (DD - 1))];
    }
    __syncthreads();
    #pragma unroll
    for (int i = 0; i < 4; i++) {
        int n = n0 + ty + i * 8, k = k0 + tx;
        float v = st[tx][ty + i * 8];
        unsigned short hs, ls;
        split2(v, hs, ls);
        size_t a = ((size_t)(n >> 4) * (K >> 3) + (k >> 3)) * 128 + ((n & 15) << 3) + (k & 7);
        Fhi[a] = (short)hs;
        Flo[a] = (short)ls;
    }
}

// All-edge gather: Gbig (FO hi/lo, K=4096) = split(per-edge neighbor sums of fp32 h);
// abuf = deg-weighted prop bias.
__global__ __launch_bounds__(256) void k_gather_all(const float* __restrict__ h,
                                                    const int* __restrict__ cnt2,
                                                    const unsigned short* __restrict__ idx,
                                                    const float* __restrict__ bp,
                                                    short* __restrict__ Gbhi,
                                                    short* __restrict__ Gblo,
                                                    float* __restrict__ abuf) {
    int n = blockIdx.x, t = threadIdx.x;
    float s0 = 0.f, s1 = 0.f;
    size_t abase = ((size_t)(n >> 4) * 512) * 128 + ((n & 15) << 3) + ((t & 3) << 1);
    #pragma unroll 1
    for (int e = 0; e < NEDGE; e++) {
        int m = cnt2[n * NEDGE + e];
        float deg = (float)m;
        if (m > MAXE) m = MAXE;
        const unsigned short* row = idx + ((size_t)n * NEDGE + e) * MAXE;
        float a0 = 0.f, a1 = 0.f;
        int i = 0;
        for (; i + 4 <= m; i += 4) {
            const float* h0 = h + (size_t)row[i]     * DD + 2 * t;
            const float* h1 = h + (size_t)row[i + 1] * DD + 2 * t;
            const float* h2 = h + (size_t)row[i + 2] * DD + 2 * t;
            const float* h3 = h + (size_t)row[i + 3] * DD + 2 * t;
            a0 += h0[0] + h1[0] + h2[0] + h3[0];
            a1 += h0[1] + h1[1] + h2[1] + h3[1];
        }
        for (; i < m; i++) {
            const float* hp = h + (size_t)row[i] * DD + 2 * t;
            a0 += hp[0];
            a1 += hp[1];
        }
        unsigned short h0s, l0s, h1s, l1s;
        split2(a0, h0s, l0s);
        split2(a1, h1s, l1s);
        size_t a = abase + (size_t)(e * 64 + (t >> 2)) * 128;
        *(unsigned*)(Gbhi + a) = (unsigned)h0s | ((unsigned)h1s << 16);
        *(unsigned*)(Gblo + a) = (unsigned)l0s | ((unsigned)l1s << 16);
        s0 += deg * bp[e * DD + 2 * t];
        s1 += deg * bp[e * DD + 2 * t + 1];
    }
    abuf[(size_t)n * DD + 2 * t]     = s0;
    abuf[(size_t)n * DD + 2 * t + 1] = s1;
}

// Split-bf16 MFMA GEMM on FO operands: C = (Ahi+Alo)@(Bhi+Blo)^T (3 products), fp32 acc.
// Block 64(M)x32(N), 4 waves (2m x 2n), wave 32x16. BK=64, LDS dbuf (48 KB),
// 1 barrier/iter, VGPR staging. XCD-banded swizzle.
// MODE 0 (prop): K=4096, A=Gbig. v = acc + abuf[o]; Ga = split(v).
// MODE 1 (zr):   K=1024 (A seg: Ga|HB), N=1024. col<512: zbuf=sigmoid(v+b0);
//                else RH = split(sigmoid(v+b1)*h).
// MODE 2 (fin):  K=1024 (A seg: Ga|RH). hn=(1-z)h+z*tanh(v+b0); h, HB, outF.
template<int MODE>
__global__ __launch_bounds__(256, 3) void k_gemm6(
    const short* __restrict__ A0hi, const short* __restrict__ A0lo,
    const short* __restrict__ A1hi, const short* __restrict__ A1lo,
    const short* __restrict__ Bhi,  const short* __restrict__ Blo, int K,
    const float* __restrict__ bias0, const float* __restrict__ bias1,
    float* __restrict__ zbuf,
    float* __restrict__ h,
    short* __restrict__ Ohi, short* __restrict__ Olo,
    float* __restrict__ outF) {

    __shared__ short S[2][24][512];   // 2 bufs x 24 slots x 1KB = 48 KB

    const int tid = threadIdx.x;
    const int lane = tid & 63;
    const int wave = tid >> 6;
    const int wm = wave >> 1;          // m-half (32 rows)
    const int wn = wave & 1;           // n-tile (16 cols)
    const int quad = lane >> 4;
    const int l16 = lane & 15;

    // XCD-banded swizzle (gridDim.y == 32 for all grids here)
    const int pbid = blockIdx.y * gridDim.x + blockIdx.x;
    const int bx = pbid >> 5;
    const int by = (pbid & 7) * 4 + ((pbid >> 3) & 3);
    const int blockM = by * 64;
    const int blockN = bx * 32;
    const int mt0 = blockM >> 4, nt0 = blockN >> 4;
    const int KCB = K >> 3;            // B kchunk stride

    floatx4 acc[2];
    acc[0] = (floatx4){0.f, 0.f, 0.f, 0.f};
    acc[1] = (floatx4){0.f, 0.f, 0.f, 0.f};

    // slots: 0..7 A-hi (mt=s>>1, ks=s&1); 8..15 A-lo; 16..23 B (pl=u>>2, ks=(u>>1)&1, nt=u&1)
    auto gaddr = [&](int k0, int s) -> const short* {
        if (s < 16) {
            int pl = s >> 3;           // 0 = hi, 1 = lo
            int u = s & 7;
            int mt = u >> 1, ks = u & 1;
            if (MODE == 0) {
                const short* base = pl ? A0lo : A0hi;
                return base + ((size_t)(mt0 + mt) * 512 + (k0 >> 3) + ks * 4) * 128;
            } else {
                int seg = k0 >> 9;
                const short* base = seg ? (pl ? A1lo : A1hi) : (pl ? A0lo : A0hi);
                return base + ((size_t)(mt0 + mt) * 64 + (((k0 & 511) >> 3) + ks * 4)) * 128;
            }
        } else {
            int u = s - 16, pl = u >> 2, ks = (u >> 1) & 1, nt = u & 1;
            const short* base = pl ? Blo : Bhi;
            return base + ((size_t)(nt0 + nt) * KCB + (k0 >> 3) + ks * 4) * 128;
        }
    };

    short8 rg[6];
    #pragma unroll
    for (int j = 0; j < 6; j++)
        rg[j] = *(const short8*)(gaddr(0, j * 4 + wave) + lane * 8);
    #pragma unroll
    for (int j = 0; j < 6; j++)
        *(short8*)&S[0][j * 4 + wave][lane * 8] = rg[j];

    for (int k0 = 0; k0 < K; k0 += 64) {
        const int buf = (k0 >> 6) & 1;
        const bool more = (k0 + 64 < K);
        if (more) {
            #pragma unroll
            for (int j = 0; j < 6; j++)
                rg[j] = *(const short8*)(gaddr(k0 + 64, j * 4 + wave) + lane * 8);
        }
        __syncthreads();

        #pragma unroll
        for (int ks = 0; ks < 2; ks++) {
            short8 ah[2], al[2], bh, bl;
            #pragma unroll
            for (int mi = 0; mi < 2; mi++) {
                ah[mi] = *(const short8*)&S[buf][(wm * 2 + mi) * 2 + ks][lane * 8];
                al[mi] = *(const short8*)&S[buf][8 + (wm * 2 + mi) * 2 + ks][lane * 8];
            }
            bh = *(const short8*)&S[buf][16 + ks * 2 + wn][lane * 8];
            bl = *(const short8*)&S[buf][20 + ks * 2 + wn][lane * 8];
            #pragma unroll
            for (int mi = 0; mi < 2; mi++) {
                acc[mi] = __builtin_amdgcn_mfma_f32_16x16x32_bf16(ah[mi], bh, acc[mi], 0, 0, 0);
                acc[mi] = __builtin_amdgcn_mfma_f32_16x16x32_bf16(ah[mi], bl, acc[mi], 0, 0, 0);
                acc[mi] = __builtin_amdgcn_mfma_f32_16x16x32_bf16(al[mi], bh, acc[mi], 0, 0, 0);
            }
        }

        if (more) {
            #pragma unroll
            for (int j = 0; j < 6; j++)
                *(short8*)&S[buf ^ 1][j * 4 + wave][lane * 8] = rg[j];
        }
    }

    // C/D layout (m89-verified): elem r -> row = quad*4+r, col = l16
    #pragma unroll
    for (int mi = 0; mi < 2; mi++) {
        int gcol = blockN + wn * 16 + l16;
        #pragma unroll
        for (int r = 0; r < 4; r++) {
            int grow = blockM + wm * 32 + mi * 16 + quad * 4 + r;
            float v = acc[mi][r];
            if (MODE == 0) {
                size_t o = (size_t)grow * DD + gcol;
                fo_write(Ohi, Olo, grow, gcol, v + zbuf[o]);
            } else if (MODE == 1) {
                if (gcol < DD) {
                    size_t o = (size_t)grow * DD + gcol;
                    zbuf[o] = 1.f / (1.f + __expf(-(v + bias0[gcol])));
                } else {
                    int c = gcol - DD;
                    size_t o = (size_t)grow * DD + c;
                    float rr = 1.f / (1.f + __expf(-(v + bias1[c])));
                    fo_write(Ohi, Olo, grow, c, rr * h[o]);
                }
            } else {
                size_t o = (size_t)grow * DD + gcol;
                float zv = zbuf[o];
                float hv = h[o];
                float hn = (1.f - zv) * hv + zv * tanhf(v + bias0[gcol]);
                h[o] = hn;
                fo_write(Ohi, Olo, grow, gcol, hn);
                outF[o] = hn;
            }
        }
    }
}

extern "C" void kernel_launch(void* const* d_in, const int* in_sizes, int n_in,
                              void* d_out, int out_size, void* d_ws, size_t ws_size,
                              hipStream_t stream) {
    const float* adj = (const float*)d_in[0];
    const float* ann = (const float*)d_in[1];
    const float* Wp  = (const float*)d_in[2];
    const float* bp  = (const float*)d_in[3];
    const float* Wz  = (const float*)d_in[4];
    const float* Uz  = (const float*)d_in[5];
    const float* bz  = (const float*)d_in[6];
    const float* Wr  = (const float*)d_in[7];
    const float* Ur  = (const float*)d_in[8];
    const float* br  = (const float*)d_in[9];
    const float* Wh  = (const float*)d_in[10];
    const float* Uh  = (const float*)d_in[11];
    const float* bh  = (const float*)d_in[12];

    // workspace carve (~69 MB; ws ~512 MB per round-4 fill counters)
    char* p = (char*)d_ws;
    float* h     = (float*)p; p += (size_t)NNODE * DD * 4;          // 4 MB
    float* abuf  = (float*)p; p += (size_t)NNODE * DD * 4;          // 4 MB deg-bias -> z
    short* Gbhi  = (short*)p; p += (size_t)NNODE * KP * 2;          // 16 MB (FO K=4096)
    short* Gblo  = (short*)p; p += (size_t)NNODE * KP * 2;          // 16 MB
    short* Gahi  = (short*)p; p += (size_t)NNODE * DD * 2;          // 2 MB (FO K=512)
    short* Galo  = (short*)p; p += (size_t)NNODE * DD * 2;
    short* HBhi  = (short*)p; p += (size_t)NNODE * DD * 2;
    short* HBlo  = (short*)p; p += (size_t)NNODE * DD * 2;
    short* RHhi  = (short*)p; p += (size_t)NNODE * DD * 2;
    short* RHlo  = (short*)p; p += (size_t)NNODE * DD * 2;
    short* WpThi = (short*)p; p += (size_t)DD * KP * 2;             // 4 MB (FO N=512,K=4096)
    short* WpTlo = (short*)p; p += (size_t)DD * KP * 2;
    short* ZRhi  = (short*)p; p += (size_t)(2 * DD) * (2 * DD) * 2; // 2 MB (FO N=1024,K=1024)
    short* ZRlo  = (short*)p; p += (size_t)(2 * DD) * (2 * DD) * 2;
    short* HThi  = (short*)p; p += (size_t)DD * (2 * DD) * 2;       // 1 MB (FO N=512,K=1024)
    short* HTlo  = (short*)p; p += (size_t)DD * (2 * DD) * 2;
    unsigned short* idx = (unsigned short*)p;
    p += (size_t)NNODE * NEDGE * MAXE * 2;                          // 3 MB
    int* cnt2 = (int*)p; p += (size_t)NNODE * NEDGE * 4;

    float* outF = (float*)d_out;

    k_init<<<NNODE, 256, 0, stream>>>(ann, h, HBhi, HBlo, cnt2);
    k_build<<<NNODE, 256, 0, stream>>>(adj, cnt2, idx);
    k_transP<<<dim3(KP / 32, DD / 32), 256, 0, stream>>>(Wp, WpThi, WpTlo, KP);
    k_transG<<<dim3(32, 32), 256, 0, stream>>>(Wz, Uz, Wr, Ur, ZRhi, ZRlo);
    k_transG<<<dim3(32, 16), 256, 0, stream>>>(Wh, Uh, Wh, Uh, HThi, HTlo);

    dim3 gP(DD / 32, NNODE / 64);        // (16, 32) = 512 blocks
    dim3 gZ(2 * DD / 32, NNODE / 64);    // (32, 32) = 1024 blocks
    for (int s = 0; s < NSTEPS; s++) {
        k_gather_all<<<NNODE, 256, 0, stream>>>(h, cnt2, idx, bp, Gbhi, Gblo, abuf);
        // a = Gbig @ WpT + deg-bias -> Ga (FO hi/lo)
        k_gemm6<0><<<gP, 256, 0, stream>>>(Gbhi, Gblo, nullptr, nullptr,
                                           WpThi, WpTlo, KP, nullptr, nullptr,
                                           abuf, nullptr, Gahi, Galo, nullptr);
        // [z|r]: z -> abuf (fp32), RH = split(sigmoid(.)*h)
        k_gemm6<1><<<gZ, 256, 0, stream>>>(Gahi, Galo, HBhi, HBlo,
                                           ZRhi, ZRlo, 2 * DD, bz, br,
                                           abuf, h, RHhi, RHlo, nullptr);
        // h' = (1-z)h + z*tanh([a|rh]@[Wh;Uh]+bh) -> h, HB, d_out
        k_gemm6<2><<<gP, 256, 0, stream>>>(Gahi, Galo, RHhi, RHlo,
                                           HThi, HTlo, 2 * DD, bh, nullptr,
                                           abuf, h, HBhi, HBlo, outF);
    }
}

// Round 9
// 1518.544 us; speedup vs baseline: 1.9680x; 1.0191x over previous
//
#include <hip/hip_runtime.h>

typedef __attribute__((ext_vector_type(8))) short short8;
typedef __attribute__((ext_vector_type(4))) float floatx4;
typedef __attribute__((ext_vector_type(2))) float floatx2;

#define NSTEPS 5
#define DD 512
#define ANN 256
#define NNODE 2048
#define NEDGE 8                 // 2*E
#define NCOLS (NNODE * NEDGE)   // 16384
#define MAXE 96                 // nnz per (node,edge-type): mean 30.7, sd 5.5
#define KP (NEDGE * DD)         // 4096

// Fragment-ordered (FO) layout for [M][K] bf16:
// addr(row,k) = ((row>>4)*(K>>3) + (k>>3))*128 + ((row&15)<<3) + (k&7)
// One slot = 16 rows x 32 k = 1KB, lane l's 16B at slot_base + l*16.

__device__ inline float bf2f(unsigned short s) {
    unsigned u = ((unsigned)s) << 16;
    float f; __builtin_memcpy(&f, &u, 4);
    return f;
}
__device__ inline unsigned short f2bf(float f) {   // round-to-nearest-even
    unsigned u; __builtin_memcpy(&u, &f, 4);
    u += 0x7fffu + ((u >> 16) & 1u);
    return (unsigned short)(u >> 16);
}
__device__ inline void split2(float x, unsigned short& hi, unsigned short& lo) {
    hi = f2bf(x);
    lo = f2bf(x - bf2f(hi));
}
// split-write one element into FO hi/lo planes (K=512)
__device__ inline void fo_write(short* __restrict__ Fhi, short* __restrict__ Flo,
                                int row, int col, float v) {
    unsigned short hs, ls;
    split2(v, hs, ls);
    size_t a = ((size_t)(row >> 4) * 64 + (col >> 3)) * 128 + ((row & 15) << 3) + (col & 7);
    Fhi[a] = (short)hs;
    Flo[a] = (short)ls;
}

// h = [ann | 0] fp32; HB (FO, K=512) = split(h); cnt2 = 0
__global__ __launch_bounds__(256) void k_init(const float* __restrict__ ann,
                                              float* __restrict__ h,
                                              short* __restrict__ HBhi,
                                              short* __restrict__ HBlo,
                                              int* __restrict__ cnt2) {
    int n = blockIdx.x, t = threadIdx.x;
    int c = 2 * t;
    float v0 = 0.f, v1 = 0.f;
    if (c < ANN) {
        v0 = ann[(size_t)n * ANN + c];
        v1 = ann[(size_t)n * ANN + c + 1];
    }
    h[(size_t)n * DD + c]     = v0;
    h[(size_t)n * DD + c + 1] = v1;
    unsigned short h0, l0, h1, l1;
    split2(v0, h0, l0);
    split2(v1, h1, l1);
    size_t a = ((size_t)(n >> 4) * 64 + (t >> 2)) * 128 + ((n & 15) << 3) + ((t & 3) << 1);
    *(unsigned*)(HBhi + a) = (unsigned)h0 | ((unsigned)h1 << 16);
    *(unsigned*)(HBlo + a) = (unsigned)l0 | ((unsigned)l1 << 16);
    if (t < NEDGE) cnt2[n * NEDGE + t] = 0;
}

// fp32 0/1 adjacency -> per-(row, edge-type) source-node index lists
__global__ __launch_bounds__(256) void k_build(const float* __restrict__ adj,
                                               int* __restrict__ cnt2,
                                               unsigned short* __restrict__ idx) {
    int n = blockIdx.x;
    const float* row = adj + (size_t)n * NCOLS;
    for (int j8 = threadIdx.x; j8 < NCOLS / 8; j8 += 256) {
        floatx4 a = *(const floatx4*)(row + j8 * 8);
        floatx4 b = *(const floatx4*)(row + j8 * 8 + 4);
        unsigned nz = 0;
        #pragma unroll
        for (int i = 0; i < 4; i++) {
            if (a[i] != 0.f) nz |= 1u << i;
            if (b[i] != 0.f) nz |= 1u << (4 + i);
        }
        while (nz) {
            int i = __builtin_ctz(nz);
            nz &= nz - 1;
            int j = j8 * 8 + i;
            int e = j >> 11;
            int m = j & (NNODE - 1);
            int p = atomicAdd(&cnt2[n * NEDGE + e], 1);
            if (p < MAXE) idx[((size_t)n * NEDGE + e) * MAXE + p] = (unsigned short)m;
        }
    }
}

// Transpose+split weights into FO (hi & lo), contiguous-K source [K][512]
__global__ __launch_bounds__(256) void k_transP(const float* __restrict__ W,
                                                short* __restrict__ Fhi,
                                                short* __restrict__ Flo, int K) {
    __shared__ float st[32][33];
    int tx = threadIdx.x & 31, ty = threadIdx.x >> 5;
    int k0 = blockIdx.x * 32, n0 = blockIdx.y * 32;
    #pragma unroll
    for (int i = 0; i < 4; i++)
        st[ty + i * 8][tx] = W[(size_t)(k0 + ty + i * 8) * DD + n0 + tx];
    __syncthreads();
    #pragma unroll
    for (int i = 0; i < 4; i++) {
        int n = n0 + ty + i * 8, k = k0 + tx;
        float v = st[tx][ty + i * 8];
        unsigned short hs, ls;
        split2(v, hs, ls);
        size_t a = ((size_t)(n >> 4) * (K >> 3) + (k >> 3)) * 128 + ((n & 15) << 3) + (k & 7);
        Fhi[a] = (short)hs;
        Flo[a] = (short)ls;
    }
}

// Same, 4-quadrant source (k-half x n-half), K=1024
__global__ __launch_bounds__(256) void k_transG(const float* __restrict__ s00,
                                                const float* __restrict__ s10,
                                                const float* __restrict__ s01,
                                                const float* __restrict__ s11,
                                                short* __restrict__ Fhi,
                                                short* __restrict__ Flo) {
    __shared__ float st[32][33];
    const int K = 2 * DD;
    int tx = threadIdx.x & 31, ty = threadIdx.x >> 5;
    int k0 = blockIdx.x * 32, n0 = blockIdx.y * 32;
    const float* sk0 = (n0 < DD) ? s00 : s01;
    const float* sk1 = (n0 < DD) ? s10 : s11;
    #pragma unroll
    for (int i = 0; i < 4; i++) {
        int k = k0 + ty + i * 8;
        const float* s = (k < DD) ? sk0 : sk1;
        st[ty + i * 8][tx] = s[(size_t)(k & (DD - 1)) * DD + ((n0 + tx) & (DD - 1))];
    }
    __syncthreads();
    #pragma unroll
    for (int i = 0; i < 4; i++) {
        int n = n0 + ty + i * 8, k = k0 + tx;
        float v = st[tx][ty + i * 8];
        unsigned short hs, ls;
        split2(v, hs, ls);
        size_t a = ((size_t)(n >> 4) * (K >> 3) + (k >> 3)) * 128 + ((n & 15) << 3) + (k & 7);
        Fhi[a] = (short)hs;
        Flo[a] = (short)ls;
    }
}

// All-edge gather: Gbig (FO hi/lo, K=4096) = split(per-edge neighbor sums of fp32 h);
// abuf = deg-weighted prop bias.
// R9: idx lists staged in LDS, 8-wide unrolled fp32 loads (MLP), non-temporal
// stores for Gbig/abuf so the 36 MB write stream doesn't evict h from L2.
__global__ __launch_bounds__(256) void k_gather_all(const float* __restrict__ h,
                                                    const int* __restrict__ cnt2,
                                                    const unsigned short* __restrict__ idx,
                                                    const float* __restrict__ bp,
                                                    short* __restrict__ Gbhi,
                                                    short* __restrict__ Gblo,
                                                    float* __restrict__ abuf) {
    __shared__ unsigned short sidx[NEDGE * MAXE];
    __shared__ int scntR[NEDGE];
    int n = blockIdx.x, t = threadIdx.x;

    if (t < NEDGE) scntR[t] = cnt2[n * NEDGE + t];
    for (int j = t; j < NEDGE * MAXE; j += 256)
        sidx[j] = idx[(size_t)n * NEDGE * MAXE + j];
    __syncthreads();

    float s0 = 0.f, s1 = 0.f;
    size_t abase = ((size_t)(n >> 4) * 512) * 128 + ((n & 15) << 3) + ((t & 3) << 1);
    #pragma unroll 1
    for (int e = 0; e < NEDGE; e++) {
        int raw = scntR[e];
        float deg = (float)raw;
        int m = raw > MAXE ? MAXE : raw;
        const unsigned short* row = &sidx[e * MAXE];
        float a0 = 0.f, a1 = 0.f;
        int i = 0;
        for (; i + 8 <= m; i += 8) {
            #pragma unroll
            for (int j = 0; j < 8; j++) {
                floatx2 v = *(const floatx2*)(h + (size_t)row[i + j] * DD + 2 * t);
                a0 += v.x;
                a1 += v.y;
            }
        }
        for (; i < m; i++) {
            floatx2 v = *(const floatx2*)(h + (size_t)row[i] * DD + 2 * t);
            a0 += v.x;
            a1 += v.y;
        }
        unsigned short h0s, l0s, h1s, l1s;
        split2(a0, h0s, l0s);
        split2(a1, h1s, l1s);
        size_t a = abase + (size_t)(e * 64 + (t >> 2)) * 128;
        __builtin_nontemporal_store((unsigned)h0s | ((unsigned)h1s << 16),
                                    (unsigned*)(Gbhi + a));
        __builtin_nontemporal_store((unsigned)l0s | ((unsigned)l1s << 16),
                                    (unsigned*)(Gblo + a));
        s0 += deg * bp[e * DD + 2 * t];
        s1 += deg * bp[e * DD + 2 * t + 1];
    }
    __builtin_nontemporal_store(s0, &abuf[(size_t)n * DD + 2 * t]);
    __builtin_nontemporal_store(s1, &abuf[(size_t)n * DD + 2 * t + 1]);
}

// Split-bf16 MFMA GEMM on FO operands: C = (Ahi+Alo)@(Bhi+Blo)^T (3 products), fp32 acc.
// Block 64(M)x32(N), 4 waves (2m x 2n), wave 32x16. BK=64, LDS dbuf (48 KB),
// 1 barrier/iter, VGPR staging. XCD-banded swizzle.
// MODE 0 (prop): K=4096, A=Gbig. v = acc + abuf[o]; Ga = split(v).
// MODE 1 (zr):   K=1024 (A seg: Ga|HB), N=1024. col<512: zbuf=sigmoid(v+b0);
//                else RH = split(sigmoid(v+b1)*h).
// MODE 2 (fin):  K=1024 (A seg: Ga|RH). hn=(1-z)h+z*tanh(v+b0); h, HB, outF.
template<int MODE>
__global__ __launch_bounds__(256, 3) void k_gemm6(
    const short* __restrict__ A0hi, const short* __restrict__ A0lo,
    const short* __restrict__ A1hi, const short* __restrict__ A1lo,
    const short* __restrict__ Bhi,  const short* __restrict__ Blo, int K,
    const float* __restrict__ bias0, const float* __restrict__ bias1,
    float* __restrict__ zbuf,
    float* __restrict__ h,
    short* __restrict__ Ohi, short* __restrict__ Olo,
    float* __restrict__ outF) {

    __shared__ short S[2][24][512];   // 2 bufs x 24 slots x 1KB = 48 KB

    const int tid = threadIdx.x;
    const int lane = tid & 63;
    const int wave = tid >> 6;
    const int wm = wave >> 1;          // m-half (32 rows)
    const int wn = wave & 1;           // n-tile (16 cols)
    const int quad = lane >> 4;
    const int l16 = lane & 15;

    // XCD-banded swizzle (gridDim.y == 32 for all grids here)
    const int pbid = blockIdx.y * gridDim.x + blockIdx.x;
    const int bx = pbid >> 5;
    const int by = (pbid & 7) * 4 + ((pbid >> 3) & 3);
    const int blockM = by * 64;
    const int blockN = bx * 32;
    const int mt0 = blockM >> 4, nt0 = blockN >> 4;
    const int KCB = K >> 3;            // B kchunk stride

    floatx4 acc[2];
    acc[0] = (floatx4){0.f, 0.f, 0.f, 0.f};
    acc[1] = (floatx4){0.f, 0.f, 0.f, 0.f};

    // slots: 0..7 A-hi (mt=s>>1, ks=s&1); 8..15 A-lo; 16..23 B (pl=u>>2, ks=(u>>1)&1, nt=u&1)
    auto gaddr = [&](int k0, int s) -> const short* {
        if (s < 16) {
            int pl = s >> 3;           // 0 = hi, 1 = lo
            int u = s & 7;
            int mt = u >> 1, ks = u & 1;
            if (MODE == 0) {
                const short* base = pl ? A0lo : A0hi;
                return base + ((size_t)(mt0 + mt) * 512 + (k0 >> 3) + ks * 4) * 128;
            } else {
                int seg = k0 >> 9;
                const short* base = seg ? (pl ? A1lo : A1hi) : (pl ? A0lo : A0hi);
                return base + ((size_t)(mt0 + mt) * 64 + (((k0 & 511) >> 3) + ks * 4)) * 128;
            }
        } else {
            int u = s - 16, pl = u >> 2, ks = (u >> 1) & 1, nt = u & 1;
            const short* base = pl ? Blo : Bhi;
            return base + ((size_t)(nt0 + nt) * KCB + (k0 >> 3) + ks * 4) * 128;
        }
    };

    short8 rg[6];
    #pragma unroll
    for (int j = 0; j < 6; j++)
        rg[j] = *(const short8*)(gaddr(0, j * 4 + wave) + lane * 8);
    #pragma unroll
    for (int j = 0; j < 6; j++)
        *(short8*)&S[0][j * 4 + wave][lane * 8] = rg[j];

    for (int k0 = 0; k0 < K; k0 += 64) {
        const int buf = (k0 >> 6) & 1;
        const bool more = (k0 + 64 < K);
        if (more) {
            #pragma unroll
            for (int j = 0; j < 6; j++)
                rg[j] = *(const short8*)(gaddr(k0 + 64, j * 4 + wave) + lane * 8);
        }
        __syncthreads();

        #pragma unroll
        for (int ks = 0; ks < 2; ks++) {
            short8 ah[2], al[2], bh, bl;
            #pragma unroll
            for (int mi = 0; mi < 2; mi++) {
                ah[mi] = *(const short8*)&S[buf][(wm * 2 + mi) * 2 + ks][lane * 8];
                al[mi] = *(const short8*)&S[buf][8 + (wm * 2 + mi) * 2 + ks][lane * 8];
            }
            bh = *(const short8*)&S[buf][16 + ks * 2 + wn][lane * 8];
            bl = *(const short8*)&S[buf][20 + ks * 2 + wn][lane * 8];
            #pragma unroll
            for (int mi = 0; mi < 2; mi++) {
                acc[mi] = __builtin_amdgcn_mfma_f32_16x16x32_bf16(ah[mi], bh, acc[mi], 0, 0, 0);
                acc[mi] = __builtin_amdgcn_mfma_f32_16x16x32_bf16(ah[mi], bl, acc[mi], 0, 0, 0);
                acc[mi] = __builtin_amdgcn_mfma_f32_16x16x32_bf16(al[mi], bh, acc[mi], 0, 0, 0);
            }
        }

        if (more) {
            #pragma unroll
            for (int j = 0; j < 6; j++)
                *(short8*)&S[buf ^ 1][j * 4 + wave][lane * 8] = rg[j];
        }
    }

    // C/D layout (m89-verified): elem r -> row = quad*4+r, col = l16
    #pragma unroll
    for (int mi = 0; mi < 2; mi++) {
        int gcol = blockN + wn * 16 + l16;
        #pragma unroll
        for (int r = 0; r < 4; r++) {
            int grow = blockM + wm * 32 + mi * 16 + quad * 4 + r;
            float v = acc[mi][r];
            if (MODE == 0) {
                size_t o = (size_t)grow * DD + gcol;
                fo_write(Ohi, Olo, grow, gcol, v + zbuf[o]);
            } else if (MODE == 1) {
                if (gcol < DD) {
                    size_t o = (size_t)grow * DD + gcol;
                    zbuf[o] = 1.f / (1.f + __expf(-(v + bias0[gcol])));
                } else {
                    int c = gcol - DD;
                    size_t o = (size_t)grow * DD + c;
                    float rr = 1.f / (1.f + __expf(-(v + bias1[c])));
                    fo_write(Ohi, Olo, grow, c, rr * h[o]);
                }
            } else {
                size_t o = (size_t)grow * DD + gcol;
                float zv = zbuf[o];
                float hv = h[o];
                float hn = (1.f - zv) * hv + zv * tanhf(v + bias0[gcol]);
                h[o] = hn;
                fo_write(Ohi, Olo, grow, gcol, hn);
                outF[o] = hn;
            }
        }
    }
}

extern "C" void kernel_launch(void* const* d_in, const int* in_sizes, int n_in,
                              void* d_out, int out_size, void* d_ws, size_t ws_size,
                              hipStream_t stream) {
    const float* adj = (const float*)d_in[0];
    const float* ann = (const float*)d_in[1];
    const float* Wp  = (const float*)d_in[2];
    const float* bp  = (const float*)d_in[3];
    const float* Wz  = (const float*)d_in[4];
    const float* Uz  = (const float*)d_in[5];
    const float* bz  = (const float*)d_in[6];
    const float* Wr  = (const float*)d_in[7];
    const float* Ur  = (const float*)d_in[8];
    const float* br  = (const float*)d_in[9];
    const float* Wh  = (const float*)d_in[10];
    const float* Uh  = (const float*)d_in[11];
    const float* bh  = (const float*)d_in[12];

    // workspace carve (~69 MB; ws ~512 MB per round-4 fill counters)
    char* p = (char*)d_ws;
    float* h     = (float*)p; p += (size_t)NNODE * DD * 4;          // 4 MB
    float* abuf  = (float*)p; p += (size_t)NNODE * DD * 4;          // 4 MB deg-bias -> z
    short* Gbhi  = (short*)p; p += (size_t)NNODE * KP * 2;          // 16 MB (FO K=4096)
    short* Gblo  = (short*)p; p += (size_t)NNODE * KP * 2;          // 16 MB
    short* Gahi  = (short*)p; p += (size_t)NNODE * DD * 2;          // 2 MB (FO K=512)
    short* Galo  = (short*)p; p += (size_t)NNODE * DD * 2;
    short* HBhi  = (short*)p; p += (size_t)NNODE * DD * 2;
    short* HBlo  = (short*)p; p += (size_t)NNODE * DD * 2;
    short* RHhi  = (short*)p; p += (size_t)NNODE * DD * 2;
    short* RHlo  = (short*)p; p += (size_t)NNODE * DD * 2;
    short* WpThi = (short*)p; p += (size_t)DD * KP * 2;             // 4 MB (FO N=512,K=4096)
    short* WpTlo = (short*)p; p += (size_t)DD * KP * 2;
    short* ZRhi  = (short*)p; p += (size_t)(2 * DD) * (2 * DD) * 2; // 2 MB (FO N=1024,K=1024)
    short* ZRlo  = (short*)p; p += (size_t)(2 * DD) * (2 * DD) * 2;
    short* HThi  = (short*)p; p += (size_t)DD * (2 * DD) * 2;       // 1 MB (FO N=512,K=1024)
    short* HTlo  = (short*)p; p += (size_t)DD * (2 * DD) * 2;
    unsigned short* idx = (unsigned short*)p;
    p += (size_t)NNODE * NEDGE * MAXE * 2;                          // 3 MB
    int* cnt2 = (int*)p; p += (size_t)NNODE * NEDGE * 4;

    float* outF = (float*)d_out;

    k_init<<<NNODE, 256, 0, stream>>>(ann, h, HBhi, HBlo, cnt2);
    k_build<<<NNODE, 256, 0, stream>>>(adj, cnt2, idx);
    k_transP<<<dim3(KP / 32, DD / 32), 256, 0, stream>>>(Wp, WpThi, WpTlo, KP);
    k_transG<<<dim3(32, 32), 256, 0, stream>>>(Wz, Uz, Wr, Ur, ZRhi, ZRlo);
    k_transG<<<dim3(32, 16), 256, 0, stream>>>(Wh, Uh, Wh, Uh, HThi, HTlo);

    dim3 gP(DD / 32, NNODE / 64);        // (16, 32) = 512 blocks
    dim3 gZ(2 * DD / 32, NNODE / 64);    // (32, 32) = 1024 blocks
    for (int s = 0; s < NSTEPS; s++) {
        k_gather_all<<<NNODE, 256, 0, stream>>>(h, cnt2, idx, bp, Gbhi, Gblo, abuf);
        // a = Gbig @ WpT + deg-bias -> Ga (FO hi/lo)
        k_gemm6<0><<<gP, 256, 0, stream>>>(Gbhi, Gblo, nullptr, nullptr,
                                           WpThi, WpTlo, KP, nullptr, nullptr,
                                           abuf, nullptr, Gahi, Galo, nullptr);
        // [z|r]: z -> abuf (fp32), RH = split(sigmoid(.)*h)
        k_gemm6<1><<<gZ, 256, 0, stream>>>(Gahi, Galo, HBhi, HBlo,
                                           ZRhi, ZRlo, 2 * DD, bz, br,
                                           abuf, h, RHhi, RHlo, nullptr);
        // h' = (1-z)h + z*tanh([a|rh]@[Wh;Uh]+bh) -> h, HB, d_out
        k_gemm6<2><<<gP, 256, 0, stream>>>(Gahi, Galo, RHhi, RHlo,
                                           HThi, HTlo, 2 * DD, bh, nullptr,
                                           abuf, h, HBhi, HBlo, outF);
    }
}